// Round 2
// baseline (842.850 us; speedup 1.0000x reference)
//
#include <hip/hip_runtime.h>
#include <math.h>

// Problem dims (fixed by reference)
#define BB   8
#define TT   2048
#define CIN  512
#define DD   1024
#define MM   (BB * TT)     // 16384 rows for the GEMMs

// K1 GEMM tiling: 128x64 block tile, 256 threads, 8x4 dual micro-tile (64 accs).
// ROUND-1 LESSON: 128-acc variants spill (WRITE_SIZE 131MB->506MB, VGPR capped
// at 128 even with __launch_bounds__(256,2)).  Usable budget ~90 accs max; stay
// at 64.  This round: double-buffered LDS -> ONE barrier per K-tile (was 2).
// x-fragment LDS reads are 16-lane broadcasts, w-reads 4-lane broadcasts, so
// LDS bank BW is ~15% loaded -- the round-0 45%-duty limiter was barrier drain
// + ds_read latency at 21.5% occupancy, which this targets.
constexpr int BM = 128;
constexpr int BN = 64;
constexpr int BK = 16;
constexpr int NT = CIN / BK;   // 32 K-tiles

// K2 chunked scan: 16 chunks x 128 steps, 128-step speculative warm-up,
// explicit double-buffered register prefetch (PF-step batches).
#define NCHUNK 16
#define CLEN   (TT / NCHUNK)   // 128
#define WARM   128
#define PF     16

// softplus(z) = logaddexp(z, 0) — matches jax.nn.softplus / np.logaddexp
__device__ __forceinline__ float softplus_f(float z) {
    return fmaxf(z, 0.f) + log1pf(expf(-fabsf(z)));
}

// K1: fused dual GEMM  zd = x@Wd, zb = x@Wb  (+bias)  →  a_step, b_step
__global__ __launch_bounds__(256) void k1_gemm_act(
    const float* __restrict__ x,      // [MM, CIN]
    const float* __restrict__ Wd,     // [CIN, DD]
    const float* __restrict__ Wb,     // [CIN, DD]
    const float* __restrict__ bd,     // [DD]
    const float* __restrict__ bb,     // [DD]
    const float* __restrict__ A_log,  // [DD]
    float* __restrict__ a_out,        // [MM, DD]
    float* __restrict__ b_out)        // [MM, DD]
{
    // Double-buffered tiles.  xs transposed: xs[buf][k][m] -> x-fragment reads
    // are b128 16-lane broadcasts; scatter stores 2-way (free).  +4 pads keep
    // all write patterns <=2-way.
    __shared__ float xs [2][BK][BM + 4];   // 16896 B
    __shared__ float wds[2][BK][BN + 4];   //  8704 B
    __shared__ float wbs[2][BK][BN + 4];   //  8704 B   -> 34304 B total

    const int tid = threadIdx.x;
    const int n0  = blockIdx.x * BN;
    const int m0  = blockIdx.y * BM;
    const int tx  = tid & 15;          // col group: 4 cols each
    const int ty  = tid >> 4;          // row group: 8 rows each

    // staging indices
    const int lm = tid >> 1;           // 0..127  x row
    const int lk = (tid & 1) * 8;      // 0 or 8  (two float4 = 8 k)
    const int wr = tid >> 4;           // 0..15   w row
    const int wc = (tid & 15) * 4;     // 0..60   w col

    float accd[8][4], accb[8][4];
#pragma unroll
    for (int r = 0; r < 8; ++r)
#pragma unroll
        for (int c = 0; c < 4; ++c) { accd[r][c] = 0.f; accb[r][c] = 0.f; }

    const float* xp  = x + (size_t)(m0 + lm) * CIN + lk;
    const float* wdp = Wd + (size_t)wr * DD + n0 + wc;
    const float* wbp = Wb + (size_t)wr * DD + n0 + wc;

    // ---- preload tile 0 and stage into buffer 0 ----
    float4 xva = *(const float4*)(xp);
    float4 xvb = *(const float4*)(xp + 4);
    float4 wd0 = *(const float4*)(wdp);
    float4 wb0 = *(const float4*)(wbp);

    xs[0][lk + 0][lm] = xva.x;  xs[0][lk + 1][lm] = xva.y;
    xs[0][lk + 2][lm] = xva.z;  xs[0][lk + 3][lm] = xva.w;
    xs[0][lk + 4][lm] = xvb.x;  xs[0][lk + 5][lm] = xvb.y;
    xs[0][lk + 6][lm] = xvb.z;  xs[0][lk + 7][lm] = xvb.w;
    *(float4*)&wds[0][wr][wc] = wd0;
    *(float4*)&wbs[0][wr][wc] = wb0;
    __syncthreads();

    for (int t = 0; t < NT; ++t) {
        const int cur = t & 1;
        const int nxt = cur ^ 1;

        // issue next tile's global loads first — in flight during compute
        const int kn = (t + 1) * BK;
        if (kn < CIN) {
            xva = *(const float4*)(xp + kn);
            xvb = *(const float4*)(xp + kn + 4);
            wd0 = *(const float4*)(wdp + (size_t)kn * DD);
            wb0 = *(const float4*)(wbp + (size_t)kn * DD);
        }

        // compute tile t from buf[cur]
        const float (* __restrict__ xsc)[BM + 4] = xs[cur];
        const float (* __restrict__ wdc)[BN + 4] = wds[cur];
        const float (* __restrict__ wbc)[BN + 4] = wbs[cur];
#pragma unroll
        for (int kk = 0; kk < BK; ++kk) {
            const float4 xa  = *(const float4*)&xsc[kk][ty * 8];
            const float4 xa2 = *(const float4*)&xsc[kk][ty * 8 + 4];
            const float4 d0  = *(const float4*)&wdc[kk][tx * 4];
            const float4 c0  = *(const float4*)&wbc[kk][tx * 4];
            const float xr[8] = {xa.x, xa.y, xa.z, xa.w, xa2.x, xa2.y, xa2.z, xa2.w};
            const float wd[4] = {d0.x, d0.y, d0.z, d0.w};
            const float wb[4] = {c0.x, c0.y, c0.z, c0.w};
#pragma unroll
            for (int r = 0; r < 8; ++r) {
                const float xi = xr[r];
#pragma unroll
                for (int c = 0; c < 4; ++c) {
                    accd[r][c] = fmaf(xi, wd[c], accd[r][c]);
                    accb[r][c] = fmaf(xi, wb[c], accb[r][c]);
                }
            }
        }

        // stage tile t+1 into buf[nxt]; single barrier per tile
        if (kn < CIN) {
            xs[nxt][lk + 0][lm] = xva.x;  xs[nxt][lk + 1][lm] = xva.y;
            xs[nxt][lk + 2][lm] = xva.z;  xs[nxt][lk + 3][lm] = xva.w;
            xs[nxt][lk + 4][lm] = xvb.x;  xs[nxt][lk + 5][lm] = xvb.y;
            xs[nxt][lk + 6][lm] = xvb.z;  xs[nxt][lk + 7][lm] = xvb.w;
            *(float4*)&wds[nxt][wr][wc] = wd0;
            *(float4*)&wbs[nxt][wr][wc] = wb0;
            __syncthreads();
        }
    }

    // ---- epilogue ----
    const int nc0 = n0 + tx * 4;
    float4 bdq = *(const float4*)(bd + nc0);
    float4 bbq = *(const float4*)(bb + nc0);
    float4 alq = *(const float4*)(A_log + nc0);
    const float* bdv = (const float*)&bdq;
    const float* bbv = (const float*)&bbq;
    float Aq[4] = {expf(alq.x), expf(alq.y), expf(alq.z), expf(alq.w)};

#pragma unroll
    for (int r = 0; r < 8; ++r) {
        const int m = m0 + ty * 8 + r;
        float av[4], bv[4];
#pragma unroll
        for (int j = 0; j < 4; ++j) {
            float zd    = accd[r][j] + bdv[j];
            float delta = softplus_f(zd);
            float zb    = accb[r][j] + bbv[j];
            av[j] = expf(-delta * Aq[j]);
            bv[j] = delta * zb;
        }
        *(float4*)(a_out + (size_t)m * DD + nc0) = make_float4(av[0], av[1], av[2], av[3]);
        *(float4*)(b_out + (size_t)m * DD + nc0) = make_float4(bv[0], bv[1], bv[2], bv[3]);
    }
}

// K2: chunked speculative spiking scan with explicit register double-buffering.
// Warm-up from h=0 converges to the true state: any reset sets h=0 exactly
// (erases history); absent resets the h0-contribution decays as
// exp(-sum delta*A) <= e^-90 over 128 steps even for A=1 — far below fp32
// rounding. Chunk 0 has no warm-up (exact prefix).
__global__ __launch_bounds__(64) void k2_scan(
    const float* __restrict__ a,     // [BB, TT, DD]
    const float* __restrict__ b,     // [BB, TT, DD]
    const float* __restrict__ thr,   // [DD]
    float* __restrict__ hout,        // [BB, TT, DD]
    float* __restrict__ sout)        // [BB, TT, DD]
{
    const int gid   = blockIdx.x * 64 + threadIdx.x;   // 0..8191
    const int batch = gid >> 10;
    const int d     = gid & (DD - 1);
    const float th  = thr[d];
    const size_t base = (size_t)batch * TT * DD + d;

    const int chunk = blockIdx.y;
    const int t0    = chunk * CLEN;
    const int nwarm = (chunk == 0) ? 0 : WARM;         // 0 or 128 steps
    const int tw    = t0 - nwarm;
    const int nwb   = nwarm / PF;                      // warm batches: 0 or 8
    const int ntot  = nwb + CLEN / PF;                 // total batches: 8 or 16 (even)

    const float* ap = a + base + (size_t)tw * DD;
    const float* bp = b + base + (size_t)tw * DD;
    float* hp = hout + base + (size_t)t0 * DD;
    float* sp = sout + base + (size_t)t0 * DD;

    float a0[PF], b0[PF], a1[PF], b1[PF];
#pragma unroll
    for (int j = 0; j < PF; ++j) { a0[j] = ap[(size_t)j * DD]; b0[j] = bp[(size_t)j * DD]; }
    ap += (size_t)PF * DD; bp += (size_t)PF * DD;

    float h = 0.f;
    for (int i = 0; i < ntot; i += 2) {
        // prefetch batch i+1 (ntot even => always valid)
#pragma unroll
        for (int j = 0; j < PF; ++j) { a1[j] = ap[(size_t)j * DD]; b1[j] = bp[(size_t)j * DD]; }
        ap += (size_t)PF * DD; bp += (size_t)PF * DD;

        // compute batch i
        if (i >= nwb) {
#pragma unroll
            for (int j = 0; j < PF; ++j) {
                h = fmaf(a0[j], h, b0[j]);
                const bool spike = (h - th) > 0.f;
                *sp = spike ? 1.f : 0.f;
                h = spike ? 0.f : h;
                *hp = h;
                hp += DD; sp += DD;
            }
        } else {
#pragma unroll
            for (int j = 0; j < PF; ++j) {
                h = fmaf(a0[j], h, b0[j]);
                h = ((h - th) > 0.f) ? 0.f : h;
            }
        }

        // prefetch batch i+2
        if (i + 2 < ntot) {
#pragma unroll
            for (int j = 0; j < PF; ++j) { a0[j] = ap[(size_t)j * DD]; b0[j] = bp[(size_t)j * DD]; }
            ap += (size_t)PF * DD; bp += (size_t)PF * DD;
        }

        // compute batch i+1
        if (i + 1 >= nwb) {
#pragma unroll
            for (int j = 0; j < PF; ++j) {
                h = fmaf(a1[j], h, b1[j]);
                const bool spike = (h - th) > 0.f;
                *sp = spike ? 1.f : 0.f;
                h = spike ? 0.f : h;
                *hp = h;
                hp += DD; sp += DD;
            }
        } else {
#pragma unroll
            for (int j = 0; j < PF; ++j) {
                h = fmaf(a1[j], h, b1[j]);
                h = ((h - th) > 0.f) ? 0.f : h;
            }
        }
    }
}

// K3: in-place LayerNorm over last dim (D=1024), one block per row.
__global__ __launch_bounds__(256) void k3_ln(
    float* __restrict__ h,           // [MM, DD] in/out
    const float* __restrict__ gamma,
    const float* __restrict__ beta)
{
    const int row = blockIdx.x;
    const int tid = threadIdx.x;
    const int lane = tid & 63;
    const int wid  = tid >> 6;

    __shared__ float red[4];
    __shared__ float bc[2];

    float* rp = h + (size_t)row * DD + tid * 4;
    float4 v = *(const float4*)rp;

    float s = v.x + v.y + v.z + v.w;
#pragma unroll
    for (int off = 32; off > 0; off >>= 1) s += __shfl_down(s, off);
    if (lane == 0) red[wid] = s;
    __syncthreads();
    if (tid == 0) bc[0] = (red[0] + red[1] + red[2] + red[3]) * (1.0f / DD);
    __syncthreads();
    const float mu = bc[0];

    float dx = v.x - mu, dy = v.y - mu, dz = v.z - mu, dw = v.w - mu;
    float ss = dx * dx + dy * dy + dz * dz + dw * dw;
#pragma unroll
    for (int off = 32; off > 0; off >>= 1) ss += __shfl_down(ss, off);
    __syncthreads();
    if (lane == 0) red[wid] = ss;
    __syncthreads();
    if (tid == 0) bc[1] = (red[0] + red[1] + red[2] + red[3]) * (1.0f / DD);
    __syncthreads();
    const float inv = 1.0f / sqrtf(bc[1] + 1e-5f);

    float4 g  = *(const float4*)(gamma + tid * 4);
    float4 be = *(const float4*)(beta + tid * 4);
    float4 o;
    o.x = dx * inv * g.x + be.x;
    o.y = dy * inv * g.y + be.y;
    o.z = dz * inv * g.z + be.z;
    o.w = dw * inv * g.w + be.w;
    *(float4*)rp = o;
}

extern "C" void kernel_launch(void* const* d_in, const int* in_sizes, int n_in,
                              void* d_out, int out_size, void* d_ws, size_t ws_size,
                              hipStream_t stream) {
    const float* x     = (const float*)d_in[0];
    const float* Wd    = (const float*)d_in[1];
    const float* bd    = (const float*)d_in[2];
    const float* Wb    = (const float*)d_in[3];
    const float* bb    = (const float*)d_in[4];
    const float* A_log = (const float*)d_in[5];
    const float* thr   = (const float*)d_in[6];
    const float* gamma = (const float*)d_in[7];
    const float* beta  = (const float*)d_in[8];

    float* out    = (float*)d_out;                    // [MM, DD] LN output
    float* spikes = out + (size_t)MM * DD;            // [MM, DD]
    float* a_ws   = (float*)d_ws;                     // [MM, DD]
    float* b_ws   = a_ws + (size_t)MM * DD;           // [MM, DD]

    dim3 g1(DD / BN, MM / BM);                        // (16, 128)
    k1_gemm_act<<<g1, 256, 0, stream>>>(x, Wd, Wb, bd, bb, A_log, a_ws, b_ws);

    dim3 g2(BB * DD / 64, NCHUNK);                    // (128, 16)
    k2_scan<<<g2, 64, 0, stream>>>(a_ws, b_ws, thr, out, spikes);

    k3_ln<<<MM, 256, 0, stream>>>(out, gamma, beta);
}

// Round 3
// 667.387 us; speedup vs baseline: 1.2629x; 1.2629x over previous
//
#include <hip/hip_runtime.h>
#include <math.h>

// Problem dims (fixed by reference)
#define BB   8
#define TT   2048
#define CIN  512
#define DD   1024
#define MM   (BB * TT)     // 16384 rows for the GEMMs

// K1 GEMM tiling: 128x64 block tile, 256 threads, 8x4 dual micro-tile.
// ROUND-1 LESSON: 128-acc microtile spills (VGPR capped at 128; WRITE_SIZE 4x).
// ROUND-2 LESSON: explicit LDS double-buffer costs VGPR 92->180, occupancy
// 21.5->11.8%, k1 483->695us. The simple 2-barrier single-buffer loop at
// 92 VGPR is the compiler-friendly local optimum — DO NOT restructure k1.
constexpr int BM = 128;
constexpr int BN = 64;
constexpr int BK = 16;

// K2 chunked scan: 32 chunks x 64 steps, up-to-128-step speculative warm-up
// (nwarm = min(t0,128): chunks 0-2 exact, rest converged to < fp32 ulp),
// explicit double-buffered register prefetch (PF-step batches).
// NCHUNK 16->32 doubles resident waves (8->16 per CU) to hide HBM latency.
#define NCHUNK 32
#define CLEN   (TT / NCHUNK)   // 64
#define WARM   128
#define PF     16

// softplus(z) = logaddexp(z, 0) — matches jax.nn.softplus / np.logaddexp
__device__ __forceinline__ float softplus_f(float z) {
    return fmaxf(z, 0.f) + log1pf(expf(-fabsf(z)));
}

// K1: fused dual GEMM  zd = x@Wd, zb = x@Wb  (+bias)  →  a_step, b_step
__global__ __launch_bounds__(256) void k1_gemm_act(
    const float* __restrict__ x,      // [MM, CIN]
    const float* __restrict__ Wd,     // [CIN, DD]
    const float* __restrict__ Wb,     // [CIN, DD]
    const float* __restrict__ bd,     // [DD]
    const float* __restrict__ bb,     // [DD]
    const float* __restrict__ A_log,  // [DD]
    float* __restrict__ a_out,        // [MM, DD]
    float* __restrict__ b_out)        // [MM, DD]
{
    // xs transposed: xs[k][m] -> x-fragments are b128 reads; scatter stores 2-way (free).
    __shared__ float xs[BK][BM + 4];
    __shared__ float wds[BK][BN];
    __shared__ float wbs[BK][BN];

    const int tid = threadIdx.x;
    const int n0  = blockIdx.x * BN;
    const int m0  = blockIdx.y * BM;
    const int tx  = tid & 15;          // col group: 4 cols each
    const int ty  = tid >> 4;          // row group: 8 rows each

    // staging indices
    const int lm = tid >> 1;           // 0..127  x row
    const int lk = (tid & 1) * 8;      // 0 or 8  (two float4 = 8 k)
    const int wr = tid >> 4;           // 0..15   w row
    const int wc = (tid & 15) * 4;     // 0..60   w col

    float accd[8][4], accb[8][4];
#pragma unroll
    for (int r = 0; r < 8; ++r)
#pragma unroll
        for (int c = 0; c < 4; ++c) { accd[r][c] = 0.f; accb[r][c] = 0.f; }

    // ---- preload tile 0 into registers ----
    const float* xp  = x + (size_t)(m0 + lm) * CIN + lk;
    const float* wdp = Wd + (size_t)wr * DD + n0 + wc;
    const float* wbp = Wb + (size_t)wr * DD + n0 + wc;
    float4 xva = *(const float4*)(xp);
    float4 xvb = *(const float4*)(xp + 4);
    float4 wd0 = *(const float4*)(wdp);
    float4 wb0 = *(const float4*)(wbp);

    for (int k0 = 0; k0 < CIN; k0 += BK) {
        __syncthreads();   // previous tile's compute done
        xs[lk + 0][lm] = xva.x;  xs[lk + 1][lm] = xva.y;
        xs[lk + 2][lm] = xva.z;  xs[lk + 3][lm] = xva.w;
        xs[lk + 4][lm] = xvb.x;  xs[lk + 5][lm] = xvb.y;
        xs[lk + 6][lm] = xvb.z;  xs[lk + 7][lm] = xvb.w;
        *(float4*)&wds[wr][wc] = wd0;
        *(float4*)&wbs[wr][wc] = wb0;
        __syncthreads();

        // issue next tile's global loads (in flight during compute)
        const int kn = k0 + BK;
        if (kn < CIN) {
            xva = *(const float4*)(xp + kn);
            xvb = *(const float4*)(xp + kn + 4);
            wd0 = *(const float4*)(wdp + (size_t)kn * DD);
            wb0 = *(const float4*)(wbp + (size_t)kn * DD);
        }

#pragma unroll
        for (int kk = 0; kk < BK; ++kk) {
            float4 xa  = *(const float4*)&xs[kk][ty * 8];
            float4 xa2 = *(const float4*)&xs[kk][ty * 8 + 4];
            float4 d0  = *(const float4*)&wds[kk][tx * 4];
            float4 c0  = *(const float4*)&wbs[kk][tx * 4];
            float xr[8] = {xa.x, xa.y, xa.z, xa.w, xa2.x, xa2.y, xa2.z, xa2.w};
            float wd[4] = {d0.x, d0.y, d0.z, d0.w};
            float wb[4] = {c0.x, c0.y, c0.z, c0.w};
#pragma unroll
            for (int r = 0; r < 8; ++r) {
                const float xi = xr[r];
#pragma unroll
                for (int c = 0; c < 4; ++c) {
                    accd[r][c] = fmaf(xi, wd[c], accd[r][c]);
                    accb[r][c] = fmaf(xi, wb[c], accb[r][c]);
                }
            }
        }
    }

    // ---- epilogue ----
    const int nc0 = n0 + tx * 4;
    float4 bdq = *(const float4*)(bd + nc0);
    float4 bbq = *(const float4*)(bb + nc0);
    float4 alq = *(const float4*)(A_log + nc0);
    const float* bdv = (const float*)&bdq;
    const float* bbv = (const float*)&bbq;
    float Aq[4] = {expf(alq.x), expf(alq.y), expf(alq.z), expf(alq.w)};

#pragma unroll
    for (int r = 0; r < 8; ++r) {
        const int m = m0 + ty * 8 + r;
        float av[4], bv[4];
#pragma unroll
        for (int j = 0; j < 4; ++j) {
            float zd    = accd[r][j] + bdv[j];
            float delta = softplus_f(zd);
            float zb    = accb[r][j] + bbv[j];
            av[j] = expf(-delta * Aq[j]);
            bv[j] = delta * zb;
        }
        *(float4*)(a_out + (size_t)m * DD + nc0) = make_float4(av[0], av[1], av[2], av[3]);
        *(float4*)(b_out + (size_t)m * DD + nc0) = make_float4(bv[0], bv[1], bv[2], bv[3]);
    }
}

// K2: chunked speculative spiking scan with explicit register double-buffering.
// Warm-up from h=0 converges to the true state: any reset sets h=0 exactly
// (erases history); absent resets the h0-contribution decays as
// exp(-sum delta*A) <= e^-90 over 128 steps even for A=1 — far below fp32
// rounding. nwarm = min(t0, WARM): chunks 0..2 have exact prefixes.
__global__ __launch_bounds__(64) void k2_scan(
    const float* __restrict__ a,     // [BB, TT, DD]
    const float* __restrict__ b,     // [BB, TT, DD]
    const float* __restrict__ thr,   // [DD]
    float* __restrict__ hout,        // [BB, TT, DD]
    float* __restrict__ sout)        // [BB, TT, DD]
{
    const int gid   = blockIdx.x * 64 + threadIdx.x;   // 0..8191
    const int batch = gid >> 10;
    const int d     = gid & (DD - 1);
    const float th  = thr[d];
    const size_t base = (size_t)batch * TT * DD + d;

    const int chunk = blockIdx.y;
    const int t0    = chunk * CLEN;
    const int nwarm = (t0 < WARM) ? t0 : WARM;         // 0, 64, or 128 steps
    const int tw    = t0 - nwarm;
    const int nwb   = nwarm / PF;                      // warm batches: 0, 4, or 8
    const int ntot  = nwb + CLEN / PF;                 // total batches: 4, 8, or 12 (even)

    const float* ap = a + base + (size_t)tw * DD;
    const float* bp = b + base + (size_t)tw * DD;
    float* hp = hout + base + (size_t)t0 * DD;
    float* sp = sout + base + (size_t)t0 * DD;

    float a0[PF], b0[PF], a1[PF], b1[PF];
#pragma unroll
    for (int j = 0; j < PF; ++j) { a0[j] = ap[(size_t)j * DD]; b0[j] = bp[(size_t)j * DD]; }
    ap += (size_t)PF * DD; bp += (size_t)PF * DD;

    float h = 0.f;
    for (int i = 0; i < ntot; i += 2) {
        // prefetch batch i+1 (ntot even => always valid)
#pragma unroll
        for (int j = 0; j < PF; ++j) { a1[j] = ap[(size_t)j * DD]; b1[j] = bp[(size_t)j * DD]; }
        ap += (size_t)PF * DD; bp += (size_t)PF * DD;

        // compute batch i
        if (i >= nwb) {
#pragma unroll
            for (int j = 0; j < PF; ++j) {
                h = fmaf(a0[j], h, b0[j]);
                const bool spike = (h - th) > 0.f;
                *sp = spike ? 1.f : 0.f;
                h = spike ? 0.f : h;
                *hp = h;
                hp += DD; sp += DD;
            }
        } else {
#pragma unroll
            for (int j = 0; j < PF; ++j) {
                h = fmaf(a0[j], h, b0[j]);
                h = ((h - th) > 0.f) ? 0.f : h;
            }
        }

        // prefetch batch i+2
        if (i + 2 < ntot) {
#pragma unroll
            for (int j = 0; j < PF; ++j) { a0[j] = ap[(size_t)j * DD]; b0[j] = bp[(size_t)j * DD]; }
            ap += (size_t)PF * DD; bp += (size_t)PF * DD;
        }

        // compute batch i+1
        if (i + 1 >= nwb) {
#pragma unroll
            for (int j = 0; j < PF; ++j) {
                h = fmaf(a1[j], h, b1[j]);
                const bool spike = (h - th) > 0.f;
                *sp = spike ? 1.f : 0.f;
                h = spike ? 0.f : h;
                *hp = h;
                hp += DD; sp += DD;
            }
        } else {
#pragma unroll
            for (int j = 0; j < PF; ++j) {
                h = fmaf(a1[j], h, b1[j]);
                h = ((h - th) > 0.f) ? 0.f : h;
            }
        }
    }
}

// K3: in-place LayerNorm over last dim (D=1024), one block per row.
// Single-pass: reduce (sum, sumsq) together; var = E[x^2] - mu^2 (guarded).
// 2 barriers instead of 5.
__global__ __launch_bounds__(256) void k3_ln(
    float* __restrict__ h,           // [MM, DD] in/out
    const float* __restrict__ gamma,
    const float* __restrict__ beta)
{
    const int row = blockIdx.x;
    const int tid = threadIdx.x;
    const int lane = tid & 63;
    const int wid  = tid >> 6;

    __shared__ float reds[4], redss[4];
    __shared__ float bc[2];

    float* rp = h + (size_t)row * DD + tid * 4;
    float4 v = *(const float4*)rp;

    float s  = v.x + v.y + v.z + v.w;
    float ss = v.x * v.x + v.y * v.y + v.z * v.z + v.w * v.w;
#pragma unroll
    for (int off = 32; off > 0; off >>= 1) {
        s  += __shfl_down(s, off);
        ss += __shfl_down(ss, off);
    }
    if (lane == 0) { reds[wid] = s; redss[wid] = ss; }
    __syncthreads();
    if (tid == 0) {
        const float st  = reds[0] + reds[1] + reds[2] + reds[3];
        const float sst = redss[0] + redss[1] + redss[2] + redss[3];
        const float mu  = st * (1.0f / DD);
        bc[0] = mu;
        bc[1] = fmaxf(sst * (1.0f / DD) - mu * mu, 0.f);
    }
    __syncthreads();
    const float mu  = bc[0];
    const float inv = 1.0f / sqrtf(bc[1] + 1e-5f);

    float4 g  = *(const float4*)(gamma + tid * 4);
    float4 be = *(const float4*)(beta + tid * 4);
    float4 o;
    o.x = (v.x - mu) * inv * g.x + be.x;
    o.y = (v.y - mu) * inv * g.y + be.y;
    o.z = (v.z - mu) * inv * g.z + be.z;
    o.w = (v.w - mu) * inv * g.w + be.w;
    *(float4*)rp = o;
}

extern "C" void kernel_launch(void* const* d_in, const int* in_sizes, int n_in,
                              void* d_out, int out_size, void* d_ws, size_t ws_size,
                              hipStream_t stream) {
    const float* x     = (const float*)d_in[0];
    const float* Wd    = (const float*)d_in[1];
    const float* bd    = (const float*)d_in[2];
    const float* Wb    = (const float*)d_in[3];
    const float* bb    = (const float*)d_in[4];
    const float* A_log = (const float*)d_in[5];
    const float* thr   = (const float*)d_in[6];
    const float* gamma = (const float*)d_in[7];
    const float* beta  = (const float*)d_in[8];

    float* out    = (float*)d_out;                    // [MM, DD] LN output
    float* spikes = out + (size_t)MM * DD;            // [MM, DD]
    float* a_ws   = (float*)d_ws;                     // [MM, DD]
    float* b_ws   = a_ws + (size_t)MM * DD;           // [MM, DD]

    dim3 g1(DD / BN, MM / BM);                        // (16, 128)
    k1_gemm_act<<<g1, 256, 0, stream>>>(x, Wd, Wb, bd, bb, A_log, a_ws, b_ws);

    dim3 g2(BB * DD / 64, NCHUNK);                    // (128, 32)
    k2_scan<<<g2, 64, 0, stream>>>(a_ws, b_ws, thr, out, spikes);

    k3_ln<<<MM, 256, 0, stream>>>(out, gamma, beta);
}

// Round 4
// 654.043 us; speedup vs baseline: 1.2887x; 1.0204x over previous
//
#include <hip/hip_runtime.h>
#include <math.h>

// Problem dims (fixed by reference)
#define BB   8
#define TT   2048
#define CIN  512
#define DD   1024
#define MM   (BB * TT)     // 16384 rows for the GEMMs

// K1 GEMM tiling: 128x64 block tile, 256 threads, 8x4 dual micro-tile.
// ROUND-1 LESSON: 128-acc microtile spills (VGPR capped at 128; WRITE_SIZE 4x).
// ROUND-2 LESSON: explicit LDS double-buffer costs VGPR 92->180, occupancy
// halves, k1 483->695us.  The simple 2-barrier single-buffer loop at 92 VGPR
// is the compiler-friendly local optimum — DO NOT restructure k1.
constexpr int BM = 128;
constexpr int BN = 64;
constexpr int BK = 16;

// K2+K3 fused: 32 chunks x 64 steps, one 1024-thread block per (chunk,batch)
// = 256 blocks = 1/CU.  Each thread owns one d; scan runs in lockstep over t;
// LN is a block reduction every PF=8 steps on register-stashed h.  h_post
// NEVER goes to HBM (saves 134 MB + the whole k3 dispatch).
// WARM=64: contamination = h_start*exp(-sum delta*A); sum of 64 softplus(N(0,1))
// ~ N(45,6.4), P(sum<9) ~ 5.6 sigma -> error <= ~1e-4 worst plausible.
// Chunks 0-1 are exact (nwarm = min(t0,64)).  ROUND-3 LESSON: WARM=128 at
// NCHUNK=32 tripled read traffic and ate the occupancy gain.
#define NCHUNK 32
#define CLEN   (TT / NCHUNK)   // 64
#define WARM   64
#define PF     8
#define NWAVES 16

// softplus(z) = logaddexp(z, 0) — matches jax.nn.softplus / np.logaddexp
__device__ __forceinline__ float softplus_f(float z) {
    return fmaxf(z, 0.f) + log1pf(expf(-fabsf(z)));
}

// K1: fused dual GEMM  zd = x@Wd, zb = x@Wb  (+bias)  →  a_step, b_step
__global__ __launch_bounds__(256) void k1_gemm_act(
    const float* __restrict__ x,      // [MM, CIN]
    const float* __restrict__ Wd,     // [CIN, DD]
    const float* __restrict__ Wb,     // [CIN, DD]
    const float* __restrict__ bd,     // [DD]
    const float* __restrict__ bb,     // [DD]
    const float* __restrict__ A_log,  // [DD]
    float* __restrict__ a_out,        // [MM, DD]
    float* __restrict__ b_out)        // [MM, DD]
{
    // xs transposed: xs[k][m] -> x-fragments are b128 reads; scatter stores 2-way (free).
    __shared__ float xs[BK][BM + 4];
    __shared__ float wds[BK][BN];
    __shared__ float wbs[BK][BN];

    const int tid = threadIdx.x;
    const int n0  = blockIdx.x * BN;
    const int m0  = blockIdx.y * BM;
    const int tx  = tid & 15;          // col group: 4 cols each
    const int ty  = tid >> 4;          // row group: 8 rows each

    // staging indices
    const int lm = tid >> 1;           // 0..127  x row
    const int lk = (tid & 1) * 8;      // 0 or 8  (two float4 = 8 k)
    const int wr = tid >> 4;           // 0..15   w row
    const int wc = (tid & 15) * 4;     // 0..60   w col

    float accd[8][4], accb[8][4];
#pragma unroll
    for (int r = 0; r < 8; ++r)
#pragma unroll
        for (int c = 0; c < 4; ++c) { accd[r][c] = 0.f; accb[r][c] = 0.f; }

    // ---- preload tile 0 into registers ----
    const float* xp  = x + (size_t)(m0 + lm) * CIN + lk;
    const float* wdp = Wd + (size_t)wr * DD + n0 + wc;
    const float* wbp = Wb + (size_t)wr * DD + n0 + wc;
    float4 xva = *(const float4*)(xp);
    float4 xvb = *(const float4*)(xp + 4);
    float4 wd0 = *(const float4*)(wdp);
    float4 wb0 = *(const float4*)(wbp);

    for (int k0 = 0; k0 < CIN; k0 += BK) {
        __syncthreads();   // previous tile's compute done
        xs[lk + 0][lm] = xva.x;  xs[lk + 1][lm] = xva.y;
        xs[lk + 2][lm] = xva.z;  xs[lk + 3][lm] = xva.w;
        xs[lk + 4][lm] = xvb.x;  xs[lk + 5][lm] = xvb.y;
        xs[lk + 6][lm] = xvb.z;  xs[lk + 7][lm] = xvb.w;
        *(float4*)&wds[wr][wc] = wd0;
        *(float4*)&wbs[wr][wc] = wb0;
        __syncthreads();

        // issue next tile's global loads (in flight during compute)
        const int kn = k0 + BK;
        if (kn < CIN) {
            xva = *(const float4*)(xp + kn);
            xvb = *(const float4*)(xp + kn + 4);
            wd0 = *(const float4*)(wdp + (size_t)kn * DD);
            wb0 = *(const float4*)(wbp + (size_t)kn * DD);
        }

#pragma unroll
        for (int kk = 0; kk < BK; ++kk) {
            float4 xa  = *(const float4*)&xs[kk][ty * 8];
            float4 xa2 = *(const float4*)&xs[kk][ty * 8 + 4];
            float4 d0  = *(const float4*)&wds[kk][tx * 4];
            float4 c0  = *(const float4*)&wbs[kk][tx * 4];
            float xr[8] = {xa.x, xa.y, xa.z, xa.w, xa2.x, xa2.y, xa2.z, xa2.w};
            float wd[4] = {d0.x, d0.y, d0.z, d0.w};
            float wb[4] = {c0.x, c0.y, c0.z, c0.w};
#pragma unroll
            for (int r = 0; r < 8; ++r) {
                const float xi = xr[r];
#pragma unroll
                for (int c = 0; c < 4; ++c) {
                    accd[r][c] = fmaf(xi, wd[c], accd[r][c]);
                    accb[r][c] = fmaf(xi, wb[c], accb[r][c]);
                }
            }
        }
    }

    // ---- epilogue ----
    const int nc0 = n0 + tx * 4;
    float4 bdq = *(const float4*)(bd + nc0);
    float4 bbq = *(const float4*)(bb + nc0);
    float4 alq = *(const float4*)(A_log + nc0);
    const float* bdv = (const float*)&bdq;
    const float* bbv = (const float*)&bbq;
    float Aq[4] = {expf(alq.x), expf(alq.y), expf(alq.z), expf(alq.w)};

#pragma unroll
    for (int r = 0; r < 8; ++r) {
        const int m = m0 + ty * 8 + r;
        float av[4], bv[4];
#pragma unroll
        for (int j = 0; j < 4; ++j) {
            float zd    = accd[r][j] + bdv[j];
            float delta = softplus_f(zd);
            float zb    = accb[r][j] + bbv[j];
            av[j] = expf(-delta * Aq[j]);
            bv[j] = delta * zb;
        }
        *(float4*)(a_out + (size_t)m * DD + nc0) = make_float4(av[0], av[1], av[2], av[3]);
        *(float4*)(b_out + (size_t)m * DD + nc0) = make_float4(bv[0], bv[1], bv[2], bv[3]);
    }
}

// ---- fused scan + LayerNorm ----
// WARM_BATCH / OUT_BATCH are macros (not functions) so the __shared__ arrays
// stay in LDS address space and all array indexing is compile-time static
// (rule: runtime-indexed register arrays go to scratch).
//
// OUT_BATCH: scan PF steps stashing h in regs, write spikes inline, then
// two-pass LN reduce (sum -> mu, then sum((h-mu)^2) -> inv), write output.
// Barrier safety: psum written next batch only after all threads passed the
// pass-2 barrier (so prior readers are done); smu/sinv written only after
// the next batch's first barrier.  3 barriers per output batch.

#define WARM_BATCH(AV, BV)                                                \
    {                                                                     \
        _Pragma("unroll")                                                 \
        for (int j = 0; j < PF; ++j) {                                    \
            h = fmaf(AV[j], h, BV[j]);                                    \
            h = ((h - th) > 0.f) ? 0.f : h;                               \
        }                                                                 \
    }

#define OUT_BATCH(AV, BV)                                                 \
    {                                                                     \
        float hj[PF];                                                     \
        _Pragma("unroll")                                                 \
        for (int j = 0; j < PF; ++j) {                                    \
            h = fmaf(AV[j], h, BV[j]);                                    \
            const bool spike = (h - th) > 0.f;                            \
            sp[(size_t)j * DD] = spike ? 1.f : 0.f;                       \
            h = spike ? 0.f : h;                                          \
            hj[j] = h;                                                    \
        }                                                                 \
        sp += (size_t)PF * DD;                                            \
        float r[PF];                                                      \
        _Pragma("unroll")                                                 \
        for (int j = 0; j < PF; ++j) r[j] = hj[j];                        \
        _Pragma("unroll")                                                 \
        for (int off = 32; off > 0; off >>= 1) {                          \
            _Pragma("unroll")                                             \
            for (int j = 0; j < PF; ++j) r[j] += __shfl_down(r[j], off);  \
        }                                                                 \
        if (lane == 0) {                                                  \
            _Pragma("unroll")                                             \
            for (int j = 0; j < PF; ++j) psum[wid][j] = r[j];             \
        }                                                                 \
        __syncthreads();                                                  \
        if (d < PF) {                                                     \
            float s = 0.f;                                                \
            _Pragma("unroll")                                             \
            for (int w = 0; w < NWAVES; ++w) s += psum[w][d];             \
            smu[d] = s * (1.0f / DD);                                     \
        }                                                                 \
        __syncthreads();                                                  \
        _Pragma("unroll")                                                 \
        for (int j = 0; j < PF; ++j) {                                    \
            const float dv = hj[j] - smu[j];                              \
            r[j] = dv * dv;                                               \
        }                                                                 \
        _Pragma("unroll")                                                 \
        for (int off = 32; off > 0; off >>= 1) {                          \
            _Pragma("unroll")                                             \
            for (int j = 0; j < PF; ++j) r[j] += __shfl_down(r[j], off);  \
        }                                                                 \
        if (lane == 0) {                                                  \
            _Pragma("unroll")                                             \
            for (int j = 0; j < PF; ++j) psum[wid][j] = r[j];             \
        }                                                                 \
        __syncthreads();                                                  \
        if (d < PF) {                                                     \
            float ssum = 0.f;                                             \
            _Pragma("unroll")                                             \
            for (int w = 0; w < NWAVES; ++w) ssum += psum[w][d];          \
            sinv[d] = 1.0f / sqrtf(ssum * (1.0f / DD) + 1e-5f);           \
        }                                                                 \
        __syncthreads();                                                  \
        _Pragma("unroll")                                                 \
        for (int j = 0; j < PF; ++j) {                                    \
            const float o = (hj[j] - smu[j]) * sinv[j] * g + be;          \
            op[(size_t)j * DD] = o;                                       \
        }                                                                 \
        op += (size_t)PF * DD;                                            \
    }

__global__ __launch_bounds__(1024) void k23_scan_ln(
    const float* __restrict__ a,      // [BB, TT, DD]
    const float* __restrict__ b,      // [BB, TT, DD]
    const float* __restrict__ thr,    // [DD]
    const float* __restrict__ gamma,  // [DD]
    const float* __restrict__ beta,   // [DD]
    float* __restrict__ out,          // [BB, TT, DD]
    float* __restrict__ spikes)       // [BB, TT, DD]
{
    const int d     = threadIdx.x;     // 0..1023 — one thread per feature
    const int chunk = blockIdx.x;      // 0..31
    const int batch = blockIdx.y;      // 0..7
    const int lane  = d & 63;
    const int wid   = d >> 6;          // 0..15

    const float th = thr[d];
    const float g  = gamma[d];
    const float be = beta[d];

    const int t0    = chunk * CLEN;
    const int nwarm = (t0 < WARM) ? t0 : WARM;   // 0 or 64; chunks 0-1 exact
    const int tw    = t0 - nwarm;
    const int nwb   = nwarm / PF;                // 0 or 8
    const int ntot  = nwb + CLEN / PF;           // 8 or 16 (even)

    const size_t rowbase = (size_t)batch * TT * DD + d;
    const float* ap = a + rowbase + (size_t)tw * DD;
    const float* bp = b + rowbase + (size_t)tw * DD;
    float* op = out    + rowbase + (size_t)t0 * DD;
    float* sp = spikes + rowbase + (size_t)t0 * DD;

    __shared__ float psum[NWAVES][PF];
    __shared__ float smu[PF];
    __shared__ float sinv[PF];

    float a0[PF], b0[PF], a1[PF], b1[PF];
#pragma unroll
    for (int j = 0; j < PF; ++j) { a0[j] = ap[(size_t)j * DD]; b0[j] = bp[(size_t)j * DD]; }
    ap += (size_t)PF * DD; bp += (size_t)PF * DD;

    float h = 0.f;
    for (int i = 0; i < ntot; i += 2) {
        // prefetch batch i+1 (ntot even => always valid)
#pragma unroll
        for (int j = 0; j < PF; ++j) { a1[j] = ap[(size_t)j * DD]; b1[j] = bp[(size_t)j * DD]; }
        ap += (size_t)PF * DD; bp += (size_t)PF * DD;

        if (i >= nwb) OUT_BATCH(a0, b0) else WARM_BATCH(a0, b0)

        // prefetch batch i+2
        if (i + 2 < ntot) {
#pragma unroll
            for (int j = 0; j < PF; ++j) { a0[j] = ap[(size_t)j * DD]; b0[j] = bp[(size_t)j * DD]; }
            ap += (size_t)PF * DD; bp += (size_t)PF * DD;
        }

        if (i + 1 >= nwb) OUT_BATCH(a1, b1) else WARM_BATCH(a1, b1)
    }
}

extern "C" void kernel_launch(void* const* d_in, const int* in_sizes, int n_in,
                              void* d_out, int out_size, void* d_ws, size_t ws_size,
                              hipStream_t stream) {
    const float* x     = (const float*)d_in[0];
    const float* Wd    = (const float*)d_in[1];
    const float* bd    = (const float*)d_in[2];
    const float* Wb    = (const float*)d_in[3];
    const float* bb    = (const float*)d_in[4];
    const float* A_log = (const float*)d_in[5];
    const float* thr   = (const float*)d_in[6];
    const float* gamma = (const float*)d_in[7];
    const float* beta  = (const float*)d_in[8];

    float* out    = (float*)d_out;                    // [MM, DD] LN output
    float* spikes = out + (size_t)MM * DD;            // [MM, DD]
    float* a_ws   = (float*)d_ws;                     // [MM, DD]
    float* b_ws   = a_ws + (size_t)MM * DD;           // [MM, DD]

    dim3 g1(DD / BN, MM / BM);                        // (16, 128)
    k1_gemm_act<<<g1, 256, 0, stream>>>(x, Wd, Wb, bd, bb, A_log, a_ws, b_ws);

    dim3 g2(NCHUNK, BB);                              // (32, 8) = 256 blocks, 1/CU
    k23_scan_ln<<<g2, 1024, 0, stream>>>(a_ws, b_ws, thr, gamma, beta, out, spikes);
}

// Round 5
// 633.447 us; speedup vs baseline: 1.3306x; 1.0325x over previous
//
#include <hip/hip_runtime.h>
#include <math.h>

// Problem dims (fixed by reference)
#define BB   8
#define TT   2048
#define CIN  512
#define DD   1024
#define MM   (BB * TT)     // 16384 rows for the GEMMs

// K1 GEMM tiling: 128x64 block tile, 256 threads, 8x4 dual micro-tile.
// ROUND-1 LESSON: 128-acc microtile spills (VGPR capped at 128; WRITE_SIZE 4x).
// ROUND-2 LESSON: explicit LDS double-buffer costs VGPR 92->180, occupancy
// halves, k1 483->695us.  The simple 2-barrier single-buffer loop at 92 VGPR
// is the compiler-friendly local optimum — DO NOT restructure k1.
constexpr int BM = 128;
constexpr int BN = 64;
constexpr int BK = 16;

// K2+K3 fused: 32 chunks x 64 steps, one 512-thread block per (chunk,batch)
// = 256 blocks = 1/CU.  Each thread owns TWO adjacent features (float2 I/O);
// scan runs in lockstep over t; LN is a block reduction every PF=8 steps on
// register-stashed h.  h_post NEVER goes to HBM.
// ROUND-4 LESSON: with 1024 thr x 1 feature and a two-pass reduce, the shfl
// chain (96/thread across 16 waves) + serial 16-load cross-wave stage was the
// bottleneck (k23 = 170us vs 64us traffic floor).  This round: pre-sum 2
// features locally (total shfl halved), one-pass sum+sumsq (one shfl phase),
// parallel 128-thread cross-wave stage.  Scan order/chunking unchanged.
// WARM=64: contamination = h_start*exp(-sum delta*A); sum of 64 softplus(N(0,1))
// ~ N(45,6.4), P(sum<9) ~ 5.6 sigma -> error <= ~1e-4 worst plausible.
#define NCHUNK 32
#define CLEN   (TT / NCHUNK)   // 64
#define WARM   64
#define PF     8
#define NWAVES 8               // 512 threads

// softplus(z) = logaddexp(z, 0) — matches jax.nn.softplus / np.logaddexp
__device__ __forceinline__ float softplus_f(float z) {
    return fmaxf(z, 0.f) + log1pf(expf(-fabsf(z)));
}

// K1: fused dual GEMM  zd = x@Wd, zb = x@Wb  (+bias)  →  a_step, b_step
__global__ __launch_bounds__(256) void k1_gemm_act(
    const float* __restrict__ x,      // [MM, CIN]
    const float* __restrict__ Wd,     // [CIN, DD]
    const float* __restrict__ Wb,     // [CIN, DD]
    const float* __restrict__ bd,     // [DD]
    const float* __restrict__ bb,     // [DD]
    const float* __restrict__ A_log,  // [DD]
    float* __restrict__ a_out,        // [MM, DD]
    float* __restrict__ b_out)        // [MM, DD]
{
    // xs transposed: xs[k][m] -> x-fragments are b128 reads; scatter stores 2-way (free).
    __shared__ float xs[BK][BM + 4];
    __shared__ float wds[BK][BN];
    __shared__ float wbs[BK][BN];

    const int tid = threadIdx.x;
    const int n0  = blockIdx.x * BN;
    const int m0  = blockIdx.y * BM;
    const int tx  = tid & 15;          // col group: 4 cols each
    const int ty  = tid >> 4;          // row group: 8 rows each

    // staging indices
    const int lm = tid >> 1;           // 0..127  x row
    const int lk = (tid & 1) * 8;      // 0 or 8  (two float4 = 8 k)
    const int wr = tid >> 4;           // 0..15   w row
    const int wc = (tid & 15) * 4;     // 0..60   w col

    float accd[8][4], accb[8][4];
#pragma unroll
    for (int r = 0; r < 8; ++r)
#pragma unroll
        for (int c = 0; c < 4; ++c) { accd[r][c] = 0.f; accb[r][c] = 0.f; }

    // ---- preload tile 0 into registers ----
    const float* xp  = x + (size_t)(m0 + lm) * CIN + lk;
    const float* wdp = Wd + (size_t)wr * DD + n0 + wc;
    const float* wbp = Wb + (size_t)wr * DD + n0 + wc;
    float4 xva = *(const float4*)(xp);
    float4 xvb = *(const float4*)(xp + 4);
    float4 wd0 = *(const float4*)(wdp);
    float4 wb0 = *(const float4*)(wbp);

    for (int k0 = 0; k0 < CIN; k0 += BK) {
        __syncthreads();   // previous tile's compute done
        xs[lk + 0][lm] = xva.x;  xs[lk + 1][lm] = xva.y;
        xs[lk + 2][lm] = xva.z;  xs[lk + 3][lm] = xva.w;
        xs[lk + 4][lm] = xvb.x;  xs[lk + 5][lm] = xvb.y;
        xs[lk + 6][lm] = xvb.z;  xs[lk + 7][lm] = xvb.w;
        *(float4*)&wds[wr][wc] = wd0;
        *(float4*)&wbs[wr][wc] = wb0;
        __syncthreads();

        // issue next tile's global loads (in flight during compute)
        const int kn = k0 + BK;
        if (kn < CIN) {
            xva = *(const float4*)(xp + kn);
            xvb = *(const float4*)(xp + kn + 4);
            wd0 = *(const float4*)(wdp + (size_t)kn * DD);
            wb0 = *(const float4*)(wbp + (size_t)kn * DD);
        }

#pragma unroll
        for (int kk = 0; kk < BK; ++kk) {
            float4 xa  = *(const float4*)&xs[kk][ty * 8];
            float4 xa2 = *(const float4*)&xs[kk][ty * 8 + 4];
            float4 d0  = *(const float4*)&wds[kk][tx * 4];
            float4 c0  = *(const float4*)&wbs[kk][tx * 4];
            float xr[8] = {xa.x, xa.y, xa.z, xa.w, xa2.x, xa2.y, xa2.z, xa2.w};
            float wd[4] = {d0.x, d0.y, d0.z, d0.w};
            float wb[4] = {c0.x, c0.y, c0.z, c0.w};
#pragma unroll
            for (int r = 0; r < 8; ++r) {
                const float xi = xr[r];
#pragma unroll
                for (int c = 0; c < 4; ++c) {
                    accd[r][c] = fmaf(xi, wd[c], accd[r][c]);
                    accb[r][c] = fmaf(xi, wb[c], accb[r][c]);
                }
            }
        }
    }

    // ---- epilogue ----
    const int nc0 = n0 + tx * 4;
    float4 bdq = *(const float4*)(bd + nc0);
    float4 bbq = *(const float4*)(bb + nc0);
    float4 alq = *(const float4*)(A_log + nc0);
    const float* bdv = (const float*)&bdq;
    const float* bbv = (const float*)&bbq;
    float Aq[4] = {expf(alq.x), expf(alq.y), expf(alq.z), expf(alq.w)};

#pragma unroll
    for (int r = 0; r < 8; ++r) {
        const int m = m0 + ty * 8 + r;
        float av[4], bv[4];
#pragma unroll
        for (int j = 0; j < 4; ++j) {
            float zd    = accd[r][j] + bdv[j];
            float delta = softplus_f(zd);
            float zb    = accb[r][j] + bbv[j];
            av[j] = expf(-delta * Aq[j]);
            bv[j] = delta * zb;
        }
        *(float4*)(a_out + (size_t)m * DD + nc0) = make_float4(av[0], av[1], av[2], av[3]);
        *(float4*)(b_out + (size_t)m * DD + nc0) = make_float4(bv[0], bv[1], bv[2], bv[3]);
    }
}

// ---- fused scan + LayerNorm (512 threads, 2 features/thread) ----
// Macros keep all array indexing compile-time static (runtime-indexed register
// arrays go to scratch) and LDS arrays in scope.
//
// OUT_BATCH: scan PF steps stashing h (float2) in regs, write spikes inline,
// then ONE-PASS block reduce of (sum, sumsq) per step:
//   stage 1: per-thread local pre-sum over its 2 features (free VALU)
//   stage 2: 6-stage wave shfl for 16 values (8 sum + 8 sumsq)
//   stage 3: 128 threads pull the 8x16 partials, 3-stage shfl within 8-lane
//            groups, 16 lanes write red[] (parallel — was 2x16 serial loads)
//   stage 4: 8 threads compute mu / inv, broadcast via LDS
// 3 barriers per output batch (write-after-read safety: psum is re-written
// only after two barriers separate it from the previous batch's readers).

#define WARM_BATCH(AV, BV)                                                \
    {                                                                     \
        _Pragma("unroll")                                                 \
        for (int j = 0; j < PF; ++j) {                                    \
            h.x = fmaf(AV[j].x, h.x, BV[j].x);                            \
            h.y = fmaf(AV[j].y, h.y, BV[j].y);                            \
            h.x = ((h.x - th.x) > 0.f) ? 0.f : h.x;                       \
            h.y = ((h.y - th.y) > 0.f) ? 0.f : h.y;                       \
        }                                                                 \
    }

#define OUT_BATCH(AV, BV)                                                 \
    {                                                                     \
        float2 hj[PF];                                                    \
        _Pragma("unroll")                                                 \
        for (int j = 0; j < PF; ++j) {                                    \
            h.x = fmaf(AV[j].x, h.x, BV[j].x);                            \
            h.y = fmaf(AV[j].y, h.y, BV[j].y);                            \
            const bool kx = (h.x - th.x) > 0.f;                           \
            const bool ky = (h.y - th.y) > 0.f;                           \
            *(float2*)(sp + (size_t)j * DD) =                             \
                make_float2(kx ? 1.f : 0.f, ky ? 1.f : 0.f);              \
            h.x = kx ? 0.f : h.x;                                         \
            h.y = ky ? 0.f : h.y;                                         \
            hj[j] = h;                                                    \
        }                                                                 \
        sp += (size_t)PF * DD;                                            \
        float s[PF], ssq[PF];                                             \
        _Pragma("unroll")                                                 \
        for (int j = 0; j < PF; ++j) {                                    \
            s[j]   = hj[j].x + hj[j].y;                                   \
            ssq[j] = fmaf(hj[j].x, hj[j].x, hj[j].y * hj[j].y);           \
        }                                                                 \
        _Pragma("unroll")                                                 \
        for (int off = 32; off > 0; off >>= 1) {                          \
            _Pragma("unroll")                                             \
            for (int j = 0; j < PF; ++j) {                                \
                s[j]   += __shfl_down(s[j], off);                         \
                ssq[j] += __shfl_down(ssq[j], off);                       \
            }                                                             \
        }                                                                 \
        if (lane == 0) {                                                  \
            _Pragma("unroll")                                             \
            for (int j = 0; j < PF; ++j) {                                \
                psum[wid][j]      = s[j];                                 \
                psum[wid][j + PF] = ssq[j];                               \
            }                                                             \
        }                                                                 \
        __syncthreads();                                                  \
        if (tid < 128) {                                                  \
            const int v = tid >> 3;                                       \
            const int w = tid & 7;                                        \
            float p = psum[w][v];                                         \
            p += __shfl_down(p, 4);                                       \
            p += __shfl_down(p, 2);                                       \
            p += __shfl_down(p, 1);                                       \
            if (w == 0) red[v] = p;                                       \
        }                                                                 \
        __syncthreads();                                                  \
        if (tid < PF) {                                                   \
            const float mu  = red[tid] * (1.0f / DD);                     \
            const float var =                                             \
                fmaxf(red[tid + PF] * (1.0f / DD) - mu * mu, 0.f);        \
            smu[tid]  = mu;                                               \
            sinv[tid] = 1.0f / sqrtf(var + 1e-5f);                        \
        }                                                                 \
        __syncthreads();                                                  \
        _Pragma("unroll")                                                 \
        for (int j = 0; j < PF; ++j) {                                    \
            float2 o;                                                     \
            o.x = (hj[j].x - smu[j]) * sinv[j] * g.x + be.x;              \
            o.y = (hj[j].y - smu[j]) * sinv[j] * g.y + be.y;              \
            *(float2*)(op + (size_t)j * DD) = o;                          \
        }                                                                 \
        op += (size_t)PF * DD;                                            \
    }

__global__ __launch_bounds__(512) void k23_scan_ln(
    const float* __restrict__ a,      // [BB, TT, DD]
    const float* __restrict__ b,      // [BB, TT, DD]
    const float* __restrict__ thr,    // [DD]
    const float* __restrict__ gamma,  // [DD]
    const float* __restrict__ beta,   // [DD]
    float* __restrict__ out,          // [BB, TT, DD]
    float* __restrict__ spikes)       // [BB, TT, DD]
{
    const int tid   = threadIdx.x;     // 0..511 — two features per thread
    const int d0    = tid * 2;
    const int chunk = blockIdx.x;      // 0..31
    const int batch = blockIdx.y;      // 0..7
    const int lane  = tid & 63;
    const int wid   = tid >> 6;        // 0..7

    const float2 th = *(const float2*)(thr + d0);
    const float2 g  = *(const float2*)(gamma + d0);
    const float2 be = *(const float2*)(beta + d0);

    const int t0    = chunk * CLEN;
    const int nwarm = (t0 < WARM) ? t0 : WARM;   // 0 or 64; chunks 0-1 exact
    const int tw    = t0 - nwarm;
    const int nwb   = nwarm / PF;                // 0 or 8
    const int ntot  = nwb + CLEN / PF;           // 8 or 16 (even)

    const size_t rowbase = (size_t)batch * TT * DD + d0;
    const float* ap = a + rowbase + (size_t)tw * DD;
    const float* bp = b + rowbase + (size_t)tw * DD;
    float* op = out    + rowbase + (size_t)t0 * DD;
    float* sp = spikes + rowbase + (size_t)t0 * DD;

    __shared__ float psum[NWAVES][17];   // [wave][v], padded (banks <=2-way)
    __shared__ float red[2 * PF];
    __shared__ float smu[PF];
    __shared__ float sinv[PF];

    float2 a0[PF], b0[PF], a1[PF], b1[PF];
#pragma unroll
    for (int j = 0; j < PF; ++j) {
        a0[j] = *(const float2*)(ap + (size_t)j * DD);
        b0[j] = *(const float2*)(bp + (size_t)j * DD);
    }
    ap += (size_t)PF * DD; bp += (size_t)PF * DD;

    float2 h = make_float2(0.f, 0.f);
    for (int i = 0; i < ntot; i += 2) {
        // prefetch batch i+1 (ntot even => always valid)
#pragma unroll
        for (int j = 0; j < PF; ++j) {
            a1[j] = *(const float2*)(ap + (size_t)j * DD);
            b1[j] = *(const float2*)(bp + (size_t)j * DD);
        }
        ap += (size_t)PF * DD; bp += (size_t)PF * DD;

        if (i >= nwb) OUT_BATCH(a0, b0) else WARM_BATCH(a0, b0)

        // prefetch batch i+2
        if (i + 2 < ntot) {
#pragma unroll
            for (int j = 0; j < PF; ++j) {
                a0[j] = *(const float2*)(ap + (size_t)j * DD);
                b0[j] = *(const float2*)(bp + (size_t)j * DD);
            }
            ap += (size_t)PF * DD; bp += (size_t)PF * DD;
        }

        if (i + 1 >= nwb) OUT_BATCH(a1, b1) else WARM_BATCH(a1, b1)
    }
}

extern "C" void kernel_launch(void* const* d_in, const int* in_sizes, int n_in,
                              void* d_out, int out_size, void* d_ws, size_t ws_size,
                              hipStream_t stream) {
    const float* x     = (const float*)d_in[0];
    const float* Wd    = (const float*)d_in[1];
    const float* bd    = (const float*)d_in[2];
    const float* Wb    = (const float*)d_in[3];
    const float* bb    = (const float*)d_in[4];
    const float* A_log = (const float*)d_in[5];
    const float* thr   = (const float*)d_in[6];
    const float* gamma = (const float*)d_in[7];
    const float* beta  = (const float*)d_in[8];

    float* out    = (float*)d_out;                    // [MM, DD] LN output
    float* spikes = out + (size_t)MM * DD;            // [MM, DD]
    float* a_ws   = (float*)d_ws;                     // [MM, DD]
    float* b_ws   = a_ws + (size_t)MM * DD;           // [MM, DD]

    dim3 g1(DD / BN, MM / BM);                        // (16, 128)
    k1_gemm_act<<<g1, 256, 0, stream>>>(x, Wd, Wb, bd, bb, A_log, a_ws, b_ws);

    dim3 g2(NCHUNK, BB);                              // (32, 8) = 256 blocks, 1/CU
    k23_scan_ln<<<g2, 512, 0, stream>>>(a_ws, b_ws, thr, gamma, beta, out, spikes);
}

// Round 6
// 632.421 us; speedup vs baseline: 1.3327x; 1.0016x over previous
//
#include <hip/hip_runtime.h>
#include <math.h>

// Problem dims (fixed by reference)
#define BB   8
#define TT   2048
#define CIN  512
#define DD   1024
#define MM   (BB * TT)     // 16384 rows for the GEMMs

// K1 GEMM tiling: 128x64 block tile, 256 threads, 8x4 dual micro-tile.
// ROUND-1 LESSON: 128-acc microtile spills (VGPR capped at 128; WRITE_SIZE 4x).
// ROUND-2 LESSON: explicit LDS double-buffer costs VGPR 92->180, occupancy
// halves, k1 483->695us.  The simple 2-barrier single-buffer loop at 92 VGPR
// is the compiler-friendly local optimum — DO NOT restructure k1.
constexpr int BM = 128;
constexpr int BN = 64;
constexpr int BK = 16;

// K2+K3 fused: 32 chunks x 64 steps, one 512-thread block per (chunk,batch)
// = 256 blocks = 1/CU.  2 features/thread (float2 I/O); h_post never hits HBM.
// ROUND-5 LESSON: at 1 block/CU the load phase, the reduce (3 barriers), and
// stores serialize inside the block -> 41% of achievable BW.  This round:
// (a) issue next-batch loads BEFORE the reduce so they drain under it;
// (b) LDS transpose-reduce (trans[512][17], conflict-free) replaces the
//     6-stage shfl tree (~4.6k -> ~1.8k cy LDS-pipe per batch).
// WARM=64: contamination = h_start*exp(-sum delta*A); sum of 64 softplus(N(0,1))
// ~ N(45,6.4), P(sum<9) ~ 5.6 sigma -> error <= ~1e-4 worst plausible.
#define NCHUNK 32
#define CLEN   (TT / NCHUNK)   // 64
#define WARM   64
#define PF     8

// softplus(z) = logaddexp(z, 0) — matches jax.nn.softplus / np.logaddexp
__device__ __forceinline__ float softplus_f(float z) {
    return fmaxf(z, 0.f) + log1pf(expf(-fabsf(z)));
}

// K1: fused dual GEMM  zd = x@Wd, zb = x@Wb  (+bias)  →  a_step, b_step
__global__ __launch_bounds__(256) void k1_gemm_act(
    const float* __restrict__ x,      // [MM, CIN]
    const float* __restrict__ Wd,     // [CIN, DD]
    const float* __restrict__ Wb,     // [CIN, DD]
    const float* __restrict__ bd,     // [DD]
    const float* __restrict__ bb,     // [DD]
    const float* __restrict__ A_log,  // [DD]
    float* __restrict__ a_out,        // [MM, DD]
    float* __restrict__ b_out)        // [MM, DD]
{
    // xs transposed: xs[k][m] -> x-fragments are b128 reads; scatter stores 2-way (free).
    __shared__ float xs[BK][BM + 4];
    __shared__ float wds[BK][BN];
    __shared__ float wbs[BK][BN];

    const int tid = threadIdx.x;
    const int n0  = blockIdx.x * BN;
    const int m0  = blockIdx.y * BM;
    const int tx  = tid & 15;          // col group: 4 cols each
    const int ty  = tid >> 4;          // row group: 8 rows each

    // staging indices
    const int lm = tid >> 1;           // 0..127  x row
    const int lk = (tid & 1) * 8;      // 0 or 8  (two float4 = 8 k)
    const int wr = tid >> 4;           // 0..15   w row
    const int wc = (tid & 15) * 4;     // 0..60   w col

    float accd[8][4], accb[8][4];
#pragma unroll
    for (int r = 0; r < 8; ++r)
#pragma unroll
        for (int c = 0; c < 4; ++c) { accd[r][c] = 0.f; accb[r][c] = 0.f; }

    // ---- preload tile 0 into registers ----
    const float* xp  = x + (size_t)(m0 + lm) * CIN + lk;
    const float* wdp = Wd + (size_t)wr * DD + n0 + wc;
    const float* wbp = Wb + (size_t)wr * DD + n0 + wc;
    float4 xva = *(const float4*)(xp);
    float4 xvb = *(const float4*)(xp + 4);
    float4 wd0 = *(const float4*)(wdp);
    float4 wb0 = *(const float4*)(wbp);

    for (int k0 = 0; k0 < CIN; k0 += BK) {
        __syncthreads();   // previous tile's compute done
        xs[lk + 0][lm] = xva.x;  xs[lk + 1][lm] = xva.y;
        xs[lk + 2][lm] = xva.z;  xs[lk + 3][lm] = xva.w;
        xs[lk + 4][lm] = xvb.x;  xs[lk + 5][lm] = xvb.y;
        xs[lk + 6][lm] = xvb.z;  xs[lk + 7][lm] = xvb.w;
        *(float4*)&wds[wr][wc] = wd0;
        *(float4*)&wbs[wr][wc] = wb0;
        __syncthreads();

        // issue next tile's global loads (in flight during compute)
        const int kn = k0 + BK;
        if (kn < CIN) {
            xva = *(const float4*)(xp + kn);
            xvb = *(const float4*)(xp + kn + 4);
            wd0 = *(const float4*)(wdp + (size_t)kn * DD);
            wb0 = *(const float4*)(wbp + (size_t)kn * DD);
        }

#pragma unroll
        for (int kk = 0; kk < BK; ++kk) {
            float4 xa  = *(const float4*)&xs[kk][ty * 8];
            float4 xa2 = *(const float4*)&xs[kk][ty * 8 + 4];
            float4 d0  = *(const float4*)&wds[kk][tx * 4];
            float4 c0  = *(const float4*)&wbs[kk][tx * 4];
            float xr[8] = {xa.x, xa.y, xa.z, xa.w, xa2.x, xa2.y, xa2.z, xa2.w};
            float wd[4] = {d0.x, d0.y, d0.z, d0.w};
            float wb[4] = {c0.x, c0.y, c0.z, c0.w};
#pragma unroll
            for (int r = 0; r < 8; ++r) {
                const float xi = xr[r];
#pragma unroll
                for (int c = 0; c < 4; ++c) {
                    accd[r][c] = fmaf(xi, wd[c], accd[r][c]);
                    accb[r][c] = fmaf(xi, wb[c], accb[r][c]);
                }
            }
        }
    }

    // ---- epilogue ----
    const int nc0 = n0 + tx * 4;
    float4 bdq = *(const float4*)(bd + nc0);
    float4 bbq = *(const float4*)(bb + nc0);
    float4 alq = *(const float4*)(A_log + nc0);
    const float* bdv = (const float*)&bdq;
    const float* bbv = (const float*)&bbq;
    float Aq[4] = {expf(alq.x), expf(alq.y), expf(alq.z), expf(alq.w)};

#pragma unroll
    for (int r = 0; r < 8; ++r) {
        const int m = m0 + ty * 8 + r;
        float av[4], bv[4];
#pragma unroll
        for (int j = 0; j < 4; ++j) {
            float zd    = accd[r][j] + bdv[j];
            float delta = softplus_f(zd);
            float zb    = accb[r][j] + bbv[j];
            av[j] = expf(-delta * Aq[j]);
            bv[j] = delta * zb;
        }
        *(float4*)(a_out + (size_t)m * DD + nc0) = make_float4(av[0], av[1], av[2], av[3]);
        *(float4*)(b_out + (size_t)m * DD + nc0) = make_float4(bv[0], bv[1], bv[2], bv[3]);
    }
}

// ---- fused scan + LayerNorm (512 threads, 2 features/thread) ----
// Macros keep all register-array indexing compile-time static and LDS arrays
// in scope.  Per output batch:
//   scan PF steps (spikes written inline, h stashed in regs)
//   pre-sum (sum, sumsq) per step -> trans[tid][0..15]   (pad 17: bank-free)
//   PREFETCH next batch (loads drain under the reduce barriers)
//   bar1 -> 512-thread column sum (rows i2*32+rs: <=2-way banks) + 5-stage
//           shfl over 32 partials -> red[16]
//   bar2 -> 8 threads compute mu/inv -> smu/sinv
//   bar3 -> LN output writes
// Hazards: trans rewritten only after bar2+bar3 separate it from prior
// readers; red after bar3+bar1; smu after bar1+bar2.  All uniform branches.

#define PREFETCH(AV, BV)                                                  \
    {                                                                     \
        _Pragma("unroll")                                                 \
        for (int j = 0; j < PF; ++j) {                                    \
            AV[j] = *(const float2*)(ap + (size_t)j * DD);                \
            BV[j] = *(const float2*)(bp + (size_t)j * DD);                \
        }                                                                 \
        ap += (size_t)PF * DD; bp += (size_t)PF * DD;                     \
    }

#define WARM_SLOT(AV, BV)                                                 \
    {                                                                     \
        _Pragma("unroll")                                                 \
        for (int j = 0; j < PF; ++j) {                                    \
            h.x = fmaf(AV[j].x, h.x, BV[j].x);                            \
            h.y = fmaf(AV[j].y, h.y, BV[j].y);                            \
            h.x = ((h.x - th.x) > 0.f) ? 0.f : h.x;                       \
            h.y = ((h.y - th.y) > 0.f) ? 0.f : h.y;                       \
        }                                                                 \
    }

#define OUT_SLOT(AV, BV, PFOK)                                            \
    {                                                                     \
        float2 hj[PF];                                                    \
        _Pragma("unroll")                                                 \
        for (int j = 0; j < PF; ++j) {                                    \
            h.x = fmaf(AV[j].x, h.x, BV[j].x);                            \
            h.y = fmaf(AV[j].y, h.y, BV[j].y);                            \
            const bool kx = (h.x - th.x) > 0.f;                           \
            const bool ky = (h.y - th.y) > 0.f;                           \
            *(float2*)(sp + (size_t)j * DD) =                             \
                make_float2(kx ? 1.f : 0.f, ky ? 1.f : 0.f);              \
            h.x = kx ? 0.f : h.x;                                         \
            h.y = ky ? 0.f : h.y;                                         \
            hj[j] = h;                                                    \
        }                                                                 \
        sp += (size_t)PF * DD;                                            \
        _Pragma("unroll")                                                 \
        for (int j = 0; j < PF; ++j) {                                    \
            trans[tid][j]      = hj[j].x + hj[j].y;                       \
            trans[tid][j + PF] = fmaf(hj[j].x, hj[j].x,                   \
                                      hj[j].y * hj[j].y);                 \
        }                                                                 \
        if (PFOK) PREFETCH(AV, BV)                                        \
        __syncthreads();                                                  \
        {                                                                 \
            float p = 0.f;                                                \
            _Pragma("unroll")                                             \
            for (int i2 = 0; i2 < 16; ++i2)                               \
                p += trans[i2 * 32 + rs][rq];                             \
            p += __shfl_down(p, 16);                                      \
            p += __shfl_down(p, 8);                                       \
            p += __shfl_down(p, 4);                                       \
            p += __shfl_down(p, 2);                                       \
            p += __shfl_down(p, 1);                                       \
            if (rs == 0) red[rq] = p;                                     \
        }                                                                 \
        __syncthreads();                                                  \
        if (tid < PF) {                                                   \
            const float mu  = red[tid] * (1.0f / DD);                     \
            const float var =                                             \
                fmaxf(red[tid + PF] * (1.0f / DD) - mu * mu, 0.f);        \
            smu[tid]  = mu;                                               \
            sinv[tid] = 1.0f / sqrtf(var + 1e-5f);                        \
        }                                                                 \
        __syncthreads();                                                  \
        _Pragma("unroll")                                                 \
        for (int j = 0; j < PF; ++j) {                                    \
            float2 o;                                                     \
            o.x = (hj[j].x - smu[j]) * sinv[j] * g.x + be.x;              \
            o.y = (hj[j].y - smu[j]) * sinv[j] * g.y + be.y;              \
            *(float2*)(op + (size_t)j * DD) = o;                          \
        }                                                                 \
        op += (size_t)PF * DD;                                            \
    }

__global__ __launch_bounds__(512) void k23_scan_ln(
    const float* __restrict__ a,      // [BB, TT, DD]
    const float* __restrict__ b,      // [BB, TT, DD]
    const float* __restrict__ thr,    // [DD]
    const float* __restrict__ gamma,  // [DD]
    const float* __restrict__ beta,   // [DD]
    float* __restrict__ out,          // [BB, TT, DD]
    float* __restrict__ spikes)       // [BB, TT, DD]
{
    const int tid   = threadIdx.x;     // 0..511 — two features per thread
    const int d0    = tid * 2;
    const int chunk = blockIdx.x;      // 0..31
    const int batch = blockIdx.y;      // 0..7
    const int rq    = tid >> 5;        // 0..15: quantity (0..7 sum, 8..15 ssq)
    const int rs    = tid & 31;        // 0..31: summer index within quantity

    const float2 th = *(const float2*)(thr + d0);
    const float2 g  = *(const float2*)(gamma + d0);
    const float2 be = *(const float2*)(beta + d0);

    const int t0    = chunk * CLEN;
    const int nwarm = (t0 < WARM) ? t0 : WARM;   // 0 or 64; chunks 0-1 exact
    const int tw    = t0 - nwarm;
    const int nwb   = nwarm / PF;                // 0 or 8
    const int ntot  = nwb + CLEN / PF;           // 8 or 16 (even)

    const size_t rowbase = (size_t)batch * TT * DD + d0;
    const float* ap = a + rowbase + (size_t)tw * DD;
    const float* bp = b + rowbase + (size_t)tw * DD;
    float* op = out    + rowbase + (size_t)t0 * DD;
    float* sp = spikes + rowbase + (size_t)t0 * DD;

    __shared__ float trans[512][17];   // 34816 B, pad 17 -> bank-conflict-free
    __shared__ float red[2 * PF];
    __shared__ float smu[PF];
    __shared__ float sinv[PF];

    float2 a0[PF], b0[PF], a1[PF], b1[PF];
    PREFETCH(a0, b0)
    PREFETCH(a1, b1)

    float2 h = make_float2(0.f, 0.f);
    for (int i = 0; i < ntot; i += 2) {
        if (i >= nwb) OUT_SLOT(a0, b0, i + 2 < ntot)
        else { WARM_SLOT(a0, b0) PREFETCH(a0, b0) }

        if (i + 1 >= nwb) OUT_SLOT(a1, b1, i + 3 < ntot)
        else { WARM_SLOT(a1, b1) PREFETCH(a1, b1) }
    }
}

extern "C" void kernel_launch(void* const* d_in, const int* in_sizes, int n_in,
                              void* d_out, int out_size, void* d_ws, size_t ws_size,
                              hipStream_t stream) {
    const float* x     = (const float*)d_in[0];
    const float* Wd    = (const float*)d_in[1];
    const float* bd    = (const float*)d_in[2];
    const float* Wb    = (const float*)d_in[3];
    const float* bb    = (const float*)d_in[4];
    const float* A_log = (const float*)d_in[5];
    const float* thr   = (const float*)d_in[6];
    const float* gamma = (const float*)d_in[7];
    const float* beta  = (const float*)d_in[8];

    float* out    = (float*)d_out;                    // [MM, DD] LN output
    float* spikes = out + (size_t)MM * DD;            // [MM, DD]
    float* a_ws   = (float*)d_ws;                     // [MM, DD]
    float* b_ws   = a_ws + (size_t)MM * DD;           // [MM, DD]

    dim3 g1(DD / BN, MM / BM);                        // (16, 128)
    k1_gemm_act<<<g1, 256, 0, stream>>>(x, Wd, Wb, bd, bb, A_log, a_ws, b_ws);

    dim3 g2(NCHUNK, BB);                              // (32, 8) = 256 blocks, 1/CU
    k23_scan_ln<<<g2, 512, 0, stream>>>(a_ws, b_ws, thr, gamma, beta, out, spikes);
}